// Round 15
// baseline (984.252 us; speedup 1.0000x reference)
//
#include <hip/hip_runtime.h>

#define E_CNT 80000
#define N_NODES 10000

typedef __attribute__((ext_vector_type(8))) __bf16 bf16x8;
typedef __attribute__((ext_vector_type(4))) float f32x4;

__device__ __forceinline__ float sigmoidf_(float x) { return 1.f / (1.f + __expf(-x)); }

__device__ __forceinline__ unsigned fkey(float f) {
  unsigned u = __float_as_uint(f);
  return (u & 0x80000000u) ? ~u : (u | 0x80000000u);
}
__device__ __forceinline__ float unfkey(unsigned k) {
  unsigned u = (k & 0x80000000u) ? (k & 0x7FFFFFFFu) : ~k;
  return __uint_as_float(u);
}

// ---------------------------------------------------------------------------
// Consolidated weight prep (R14).
// ---------------------------------------------------------------------------
__global__ __launch_bounds__(256) void k_prep(
    const float* __restrict__ c1w0, const float* __restrict__ c2w0,
    const float* __restrict__ c2w1, const float* __restrict__ c2w2,
    const float* __restrict__ rw1, const float* __restrict__ rw2,
    const float* __restrict__ gwh, const float* __restrict__ gwx,
    const float* __restrict__ gwt, const float* __restrict__ pw,
    __bf16* __restrict__ w0r, __bf16* __restrict__ w0b,
    __bf16* __restrict__ w1n, __bf16* __restrict__ w2n,
    __bf16* __restrict__ rw1f, __bf16* __restrict__ rw2f,
    __bf16* __restrict__ gwhf, __bf16* __restrict__ gwxf,
    __bf16* __restrict__ gwtf, float* __restrict__ wT) {
  int i = blockIdx.x * 256 + threadIdx.x;
  if (i < 27648) {
    int ksg = i / 576, col = i % 576;
#pragma unroll
    for (int j = 0; j < 8; ++j)
      w0r[(size_t)i * 8 + j] = (__bf16)c1w0[(size_t)(ksg * 8 + j) * 768 + col];
  } else if (i < 36864) {
    int ii = i - 27648;
    int ksg = ii / 384, col = ii % 384;
#pragma unroll
    for (int j = 0; j < 8; ++j)
      w0b[(size_t)ii * 8 + j] = (__bf16)c2w0[(size_t)(ksg * 8 + j) * 384 + col];
  } else if (i < 53248) {
    int ii = i - 36864;
    int ksg = ii >> 9, col = ii & 511;
    int o = col >> 7, c = col & 127;
    const int tc[4] = {0, 128, 256, 384};
    const int bc[4] = {256, 384, 0, 128};
    const float sg[4] = {-1.f, -1.f, 1.f, 1.f};
#pragma unroll
    for (int j = 0; j < 8; ++j) {
      int kk = ksg * 8 + j;
      float v = (kk < 128) ? c2w1[(size_t)kk * 512 + tc[o] + c]
                           : sg[o] * c2w1[(size_t)(kk - 128) * 512 + bc[o] + c];
      w1n[(size_t)ii * 8 + j] = (__bf16)v;
    }
  } else if (i < 57344) {
    int ii = i - 53248;
    int ksg = ii >> 8, col = ii & 255;
    int o = col >> 7, c = col & 127;
#pragma unroll
    for (int j = 0; j < 8; ++j) {
      int kk = ksg * 8 + j;
      float v;
      if (kk < 64) v = c2w2[(size_t)kk * 256 + (o == 0 ? c : c + 128)];
      else         v = (o == 0) ? -c2w2[(size_t)(kk - 64) * 256 + c + 128]
                                :  c2w2[(size_t)(kk - 64) * 256 + c];
      w2n[(size_t)ii * 8 + j] = (__bf16)v;
    }
  } else if (i < 62464) {
    int ii = i - 57344;
    int ksg = ii / 128, col = ii % 128;
#pragma unroll
    for (int j = 0; j < 8; ++j)
      rw1f[(size_t)ii * 8 + j] = (__bf16)rw1[(size_t)(ksg * 8 + j) * 128 + col];
  } else if (i < 68608) {
    int ii = i - 62464;
    int ksg = ii / 384, col = ii % 384;
#pragma unroll
    for (int j = 0; j < 8; ++j)
      rw2f[(size_t)ii * 8 + j] = (__bf16)rw2[(size_t)(ksg * 8 + j) * 768 + col];
  } else if (i < 69120) {
    int ii = i - 68608;
    int ksg = ii / 64, col = ii % 64;
#pragma unroll
    for (int j = 0; j < 8; ++j)
      gwhf[(size_t)ii * 8 + j] = (__bf16)gwh[(size_t)(ksg * 8 + j) * 64 + col];
  } else if (i < 69632) {
    int ii = i - 69120;
    int ksg = ii / 64, col = ii % 64;
#pragma unroll
    for (int j = 0; j < 8; ++j)
      gwxf[(size_t)ii * 8 + j] = (__bf16)gwx[(size_t)(ksg * 8 + j) * 64 + col];
  } else if (i < 70656) {
    int ii = i - 69632;
    int ksg = ii / 64, col = ii % 64;
#pragma unroll
    for (int j = 0; j < 8; ++j)
      gwtf[(size_t)ii * 8 + j] = (__bf16)gwt[(size_t)(ksg * 8 + j) * 64 + col];
  } else if (i < 95232) {
    int ii = i - 70656;
    int l = ii / 8192, r = ii % 8192, ir = r / 64, o = r % 64;
    wT[ii] = pw[(size_t)(l * 64 + o) * 128 + ir];
  }
}

// ---------------------------------------------------------------------------
// Phase 1 (R14 verbatim: R10 structure + fused segmax). 4 blocks/CU.
// ---------------------------------------------------------------------------
__global__ __launch_bounds__(256, 4) void k_phase1(
    const float* __restrict__ x, const int* __restrict__ an,
    const float* __restrict__ edist, const int* __restrict__ eidx,
    const float* __restrict__ wigner,
    const float* __restrict__ semb, const float* __restrict__ temb,
    const __bf16* __restrict__ rw1f, const float* __restrict__ rb1,
    const float* __restrict__ rlnw, const float* __restrict__ rlnb,
    const __bf16* __restrict__ rw2f, const float* __restrict__ rb2,
    const __bf16* __restrict__ w0r, const float* __restrict__ b0,
    const float* __restrict__ lnaw, const float* __restrict__ lnab,
    const float* __restrict__ adot,
    float* __restrict__ ws_attn, float* __restrict__ ws_apre,
    unsigned* __restrict__ segk)
{
  __shared__ __align__(16) float pool[6160];
  __shared__ __align__(16) float bufB[3136];
  __shared__ float wgs[432];
  __shared__ int sidx[16], tidx[16], ansh[16], anth[16];

  const int tid = threadIdx.x;
  const int e0 = blockIdx.x * 16;
  const int lane = tid & 63, wv4 = tid >> 6;
  const int erow = lane & 15, g = lane >> 4;

  __bf16* xe_bf = (__bf16*)pool;
  float* sb = bufB;
  __bf16* sb_bf = (__bf16*)(bufB + 2112);
  __bf16* a_lds2 = (__bf16*)bufB;

  if (tid < 16) {
    int s = eidx[e0 + tid], t = eidx[E_CNT + e0 + tid];
    sidx[tid] = s; tidx[tid] = t; ansh[tid] = an[s]; anth[tid] = an[t];
  }
  for (int i = tid; i < 432; i += 256) {
    int e = i / 27, r = i % 27, kk = r / 9, j = r % 9;
    int row = (kk == 0) ? 0 : (kk == 1 ? 2 : 6);
    wgs[i] = wigner[(size_t)(e0 + e) * 81 + row * 9 + j];
  }
  __syncthreads();

  for (int i = tid; i < 16 * 320; i += 256) {
    int e = i / 320, c = i % 320;
    float v;
    if (c < 64)       v = edist[(size_t)(e0 + e) * 64 + c];
    else if (c < 192) v = semb[ansh[e] * 128 + (c - 64)];
    else              v = temb[anth[e] * 128 + (c - 192)];
    xe_bf[(((c >> 3) * 16 + e) << 3) + (c & 7)] = (__bf16)v;
  }
  __syncthreads();

  {
    bf16x8 af2[10];
#pragma unroll
    for (int ks = 0; ks < 10; ++ks)
      af2[ks] = *(const bf16x8*)(xe_bf + ((ks * 4 + g) * 16 + erow) * 8);
#pragma unroll 1
    for (int tt = 0; tt < 2; ++tt) {
      int col = (wv4 * 2 + tt) * 16 + erow;
      f32x4 acc = {0.f, 0.f, 0.f, 0.f};
#pragma unroll
      for (int ks = 0; ks < 10; ++ks)
        acc = __builtin_amdgcn_mfma_f32_16x16x32_bf16(
            af2[ks], *(const bf16x8*)(rw1f + ((size_t)((ks * 4 + g) * 128) + col) * 8), acc, 0, 0, 0);
      float bb = rb1[col];
#pragma unroll
      for (int r = 0; r < 4; ++r) sb[(g * 4 + r) * 132 + col] = acc[r] + bb;
    }
  }
  __syncthreads();

  {
    int wid = tid >> 6, ln = tid & 63;
    for (int e = wid; e < 16; e += 4) {
      float v0 = sb[e * 132 + ln], v1 = sb[e * 132 + ln + 64];
      float s1 = v0 + v1, s2 = v0 * v0 + v1 * v1;
#pragma unroll
      for (int m = 32; m >= 1; m >>= 1) {
        s1 += __shfl_xor(s1, m);
        s2 += __shfl_xor(s2, m);
      }
      float mu = s1 * (1.f / 128.f);
      float var = s2 * (1.f / 128.f) - mu * mu;
      float rstd = rsqrtf(var + 1e-5f);
      float y0 = (v0 - mu) * rstd * rlnw[ln] + rlnb[ln];
      float y1 = (v1 - mu) * rstd * rlnw[ln + 64] + rlnb[ln + 64];
      sb[e * 132 + ln]      = y0 * sigmoidf_(y0) * (1.f / 0.6f);
      sb[e * 132 + ln + 64] = y1 * sigmoidf_(y1) * (1.f / 0.6f);
    }
  }
  __syncthreads();

  {
    int ksg = tid >> 4, e = tid & 15;
    const float* sp = sb + e * 132 + ksg * 8;
    float4 u0 = *(const float4*)sp;
    float4 u1 = *(const float4*)(sp + 4);
    bf16x8 v;
    v[0] = (__bf16)u0.x; v[1] = (__bf16)u0.y; v[2] = (__bf16)u0.z; v[3] = (__bf16)u0.w;
    v[4] = (__bf16)u1.x; v[5] = (__bf16)u1.y; v[6] = (__bf16)u1.z; v[7] = (__bf16)u1.w;
    *(bf16x8*)(sb_bf + (ksg * 16 + e) * 8) = v;
  }
  __syncthreads();

  float* rbuf = pool;
  {
    bf16x8 af3[4];
#pragma unroll
    for (int ks = 0; ks < 4; ++ks)
      af3[ks] = *(const bf16x8*)(sb_bf + ((ks * 4 + g) * 16 + erow) * 8);
#pragma unroll 1
    for (int tt = 0; tt < 6; ++tt) {
      int col = (wv4 * 6 + tt) * 16 + erow;
      f32x4 acc = {0.f, 0.f, 0.f, 0.f};
#pragma unroll
      for (int ks = 0; ks < 4; ++ks)
        acc = __builtin_amdgcn_mfma_f32_16x16x32_bf16(
            af3[ks], *(const bf16x8*)(rw2f + ((size_t)((ks * 4 + g) * 384) + col) * 8), acc, 0, 0, 0);
      float bb = rb2[col];
#pragma unroll
      for (int r = 0; r < 4; ++r) rbuf[(g * 4 + r) * 385 + col] = acc[r] + bb;
    }
  }
  __syncthreads();

  {
    int e = tid & 15, cg = tid >> 4;
    int c0 = cg * 8;
    const float* xb = (c0 < 64) ? (x + (size_t)sidx[e] * 576 + c0)
                                : (x + (size_t)tidx[e] * 576 + (c0 - 64));
    float xc[9][8];
#pragma unroll
    for (int j = 0; j < 9; ++j) {
      float4 u0 = *(const float4*)(xb + j * 64);
      float4 u1 = *(const float4*)(xb + j * 64 + 4);
      xc[j][0] = u0.x; xc[j][1] = u0.y; xc[j][2] = u0.z; xc[j][3] = u0.w;
      xc[j][4] = u1.x; xc[j][5] = u1.y; xc[j][6] = u1.z; xc[j][7] = u1.w;
    }
#pragma unroll
    for (int kk = 0; kk < 3; ++kk) {
      float wv[9];
#pragma unroll
      for (int j = 0; j < 9; ++j) wv[j] = wgs[e * 27 + kk * 9 + j];
      __bf16* ap = a_lds2 + ((kk * 16 + cg) * 16 + e) * 8;
#pragma unroll
      for (int cu = 0; cu < 8; ++cu) {
        float m = 0.f;
#pragma unroll
        for (int j = 0; j < 9; ++j) m += wv[j] * xc[j][cu];
        int colc = kk * 128 + c0 + cu;
        ap[cu] = (__bf16)(m * rbuf[e * 385 + colc]);
      }
    }
  }
  __syncthreads();

  float* sb5 = pool;
  {
    bf16x8 af[12];
#pragma unroll
    for (int ks = 0; ks < 12; ++ks)
      af[ks] = *(const bf16x8*)(a_lds2 + ((ks * 4 + g) * 16 + erow) * 8);
#pragma unroll 1
    for (int tt = 0; tt < 9; ++tt) {
      int tile = wv4 * 9 + tt;
      int col = tile * 16 + erow;
      f32x4 acc = {0.f, 0.f, 0.f, 0.f};
#pragma unroll
      for (int ks = 0; ks < 12; ++ks) {
        bf16x8 bf = *(const bf16x8*)(w0r + ((size_t)((ks * 4 + g) * 576) + col) * 8);
        acc = __builtin_amdgcn_mfma_f32_16x16x32_bf16(af[ks], bf, acc, 0, 0, 0);
      }
      if (tile < 16) {
#pragma unroll
        for (int r = 0; r < 4; ++r) sb5[(g * 4 + r) * 260 + col] = acc[r];
      } else {
        float bb = b0[col];
#pragma unroll
        for (int r = 0; r < 4; ++r)
          ws_attn[(size_t)(e0 + g * 4 + r) * 320 + (col - 256)] = acc[r] + bb;
      }
    }
  }
  __syncthreads();

  {
    float bb = b0[tid];
    int h = tid >> 5, kk = tid & 31;
    float lw = lnaw[kk], lb = lnab[kk], ad = adot[h * 32 + kk];
#pragma unroll
    for (int e = 0; e < 16; ++e) {
      float v = sb5[e * 260 + tid] + bb;
      float s1 = v, s2 = v * v;
#pragma unroll
      for (int m = 16; m >= 1; m >>= 1) {
        s1 += __shfl_xor(s1, m);
        s2 += __shfl_xor(s2, m);
      }
      float mu = s1 * (1.f / 32.f);
      float var = s2 * (1.f / 32.f) - mu * mu;
      float rstd = rsqrtf(var + 1e-5f);
      float xn = (v - mu) * rstd * lw + lb;
      float sl = 0.6f * xn + 0.4f * xn * (2.f * sigmoidf_(xn) - 1.f);
      float p = sl * ad;
#pragma unroll
      for (int m = 16; m >= 1; m >>= 1) p += __shfl_xor(p, m);
      if (kk == 0) {
        ws_apre[(size_t)(e0 + e) * 8 + h] = p;
        atomicMax(&segk[tidx[e] * 8 + h], fkey(p));
      }
    }
  }
}

// ---------------------------------------------------------------------------
// exp-sum (segmax fused into phase1)
// ---------------------------------------------------------------------------
__global__ __launch_bounds__(256) void k_expsum(const float* __restrict__ apre,
                                                const int* __restrict__ eidx,
                                                const unsigned* __restrict__ segk,
                                                float* __restrict__ ex_out,
                                                float* __restrict__ denom) {
  int idx = blockIdx.x * 256 + threadIdx.x;
  if (idx >= E_CNT * 8) return;
  int e = idx >> 3, h = idx & 7;
  int t = eidx[E_CNT + e];
  float m = unfkey(segk[t * 8 + h]);
  float ex = __expf(apre[idx] - m);
  ex_out[idx] = ex;
  atomicAdd(&denom[t * 8 + h], ex);
}

// ---------------------------------------------------------------------------
// Phase 2: R13 structure (single-acc chains), launch bound (256,5) —
// VGPR use is 84 < 512/5=102, so more resident blocks at no spill cost.
// ---------------------------------------------------------------------------
__global__ __launch_bounds__(256, 5) void k_phase2(
    const float* __restrict__ x, const int* __restrict__ eidx,
    const float* __restrict__ t_ij, const float* __restrict__ rl_ij,
    const float* __restrict__ winv,
    const __bf16* __restrict__ gwhf, const __bf16* __restrict__ gwxf, const __bf16* __restrict__ gwtf,
    const __bf16* __restrict__ w0b, const float* __restrict__ b0,
    const __bf16* __restrict__ w1n, const __bf16* __restrict__ w2n,
    const float* __restrict__ ws_attn, const float* __restrict__ ws_ex,
    const float* __restrict__ denom,
    float* __restrict__ node)
{
  __shared__ __align__(16) __bf16 mb[9 * 8 * 16 * 8];
  __shared__ __align__(16) __bf16 tbf[16 * 16 * 8];
  __shared__ float wib[16 * 81];
  __shared__ float alp[128];
  __shared__ float rlb[128];
  __shared__ float malp[16];
  __shared__ int tnode[16];

  const int tid = threadIdx.x;
  const int e0 = blockIdx.x * 16;
  const int lane = tid & 63, wv = tid >> 6;
  const int e16 = lane & 15, g = lane >> 4;

  if (tid < 16) tnode[tid] = eidx[E_CNT + e0 + tid];
  __syncthreads();

  if (tid < 128) {
    int e = tid >> 3, h = tid & 7;
    float ex = ws_ex[(size_t)(e0 + e) * 8 + h];
    alp[tid] = ex / (denom[tnode[e] * 8 + h] + 1e-16f);
  } else {
    int i = tid - 128;
    rlb[i] = rl_ij[(size_t)(e0 + (i >> 3)) * 8 + (i & 7)];
  }
  for (int i = tid; i < 16 * 81; i += 256)
    wib[i] = winv[(size_t)(e0 + i / 81) * 81 + i % 81];

  for (int i = tid; i < 1152; i += 256) {
    int e = i / 72, rk = i % 72;
    const float* sp = x + (size_t)tnode[e] * 576 + rk * 8;
    float4 u0 = *(const float4*)sp;
    float4 u1 = *(const float4*)(sp + 4);
    bf16x8 v;
    v[0] = (__bf16)u0.x; v[1] = (__bf16)u0.y; v[2] = (__bf16)u0.z; v[3] = (__bf16)u0.w;
    v[4] = (__bf16)u1.x; v[5] = (__bf16)u1.y; v[6] = (__bf16)u1.z; v[7] = (__bf16)u1.w;
    *(bf16x8*)(mb + ((size_t)rk * 16 + e) * 8) = v;
  }
  {
    int e = tid >> 4, ksg = tid & 15;
    const float* sp = t_ij + (size_t)(e0 + e) * 128 + ksg * 8;
    float4 u0 = *(const float4*)sp;
    float4 u1 = *(const float4*)(sp + 4);
    bf16x8 v;
    v[0] = (__bf16)u0.x; v[1] = (__bf16)u0.y; v[2] = (__bf16)u0.z; v[3] = (__bf16)u0.w;
    v[4] = (__bf16)u1.x; v[5] = (__bf16)u1.y; v[6] = (__bf16)u1.z; v[7] = (__bf16)u1.w;
    *(bf16x8*)(tbf + ((size_t)ksg * 16 + e) * 8) = v;
  }
  __syncthreads();
  if (tid < 16) {
    float s = 0.f;
#pragma unroll
    for (int h = 0; h < 8; ++h) s += alp[tid * 8 + h];
    malp[tid] = s * 0.125f;
  }
  __syncthreads();

  // ---- gates (per-wave o-tile) + fused combine -> M0..M8 in registers ----
  f32x4 M0, M1, M2, M3, M4, M5, M6, M7, M8;
  {
    const int c = wv * 16 + e16;
#define MF(a, b, acc) acc = __builtin_amdgcn_mfma_f32_16x16x32_bf16(a, b, acc, 0, 0, 0)
#define MBF(row, ksg) (*(const bf16x8*)(mb + (((row) * 8 + (ksg)) * 16 + e16) * 8))
    f32x4 tv4;
    {
      f32x4 acc = {0.f, 0.f, 0.f, 0.f};
#pragma unroll
      for (int ks = 0; ks < 4; ++ks)
        MF(*(const bf16x8*)(tbf + ((ks * 4 + g) * 16 + e16) * 8),
           *(const bf16x8*)(gwtf + ((size_t)((ks * 4 + g) * 64) + c) * 8), acc);
#pragma unroll
      for (int r = 0; r < 4; ++r) { float v = acc[r]; tv4[r] = v * sigmoidf_(v); }
    }
    f32x4 hv4;
    {
      f32x4 acc = {0.f, 0.f, 0.f, 0.f};
      MF(MBF(0, g), *(const bf16x8*)(gwhf + ((size_t)(g * 64) + c) * 8), acc);
      MF(MBF(0, 4 + g), *(const bf16x8*)(gwhf + ((size_t)((4 + g) * 64) + c) * 8), acc);
#pragma unroll
      for (int r = 0; r < 4; ++r) { float v = acc[r]; hv4[r] = v * sigmoidf_(v); }
    }
    f32x4 osv, od0v, od1v, ot0v, ot1v;
#pragma unroll
    for (int r = 0; r < 4; ++r) {
      int e = g * 4 + r;
      float ml = malp[e];
      const float* wsb = ws_attn + (size_t)(e0 + e) * 320;
      osv[r]  = wsb[c] * ml;
      od0v[r] = wsb[64 + c] * ml;
      od1v[r] = wsb[128 + c] * ml;
      ot0v[r] = wsb[192 + c] * ml;
      ot1v[r] = wsb[256 + c] * ml;
    }
#pragma unroll
    for (int r = 0; r < 4; ++r) M0[r] = osv[r] * hv4[r];
    bf16x8 bx0 = *(const bf16x8*)(gwxf + ((size_t)(g * 64) + c) * 8);
    bf16x8 bx1 = *(const bf16x8*)(gwxf + ((size_t)((4 + g) * 64) + c) * 8);
#define XROW(rr, MV, odv, otv, jj)                                        \
    {                                                                     \
      f32x4 acc = {0.f, 0.f, 0.f, 0.f};                                   \
      MF(MBF(rr, g), bx0, acc);                                           \
      MF(MBF(rr, 4 + g), bx1, acc);                                       \
      _Pragma("unroll")                                                   \
      for (int r = 0; r < 4; ++r) {                                       \
        int e = g * 4 + r;                                                \
        MV[r] = odv[r] * acc[r] + otv[r] * tv4[r] * rlb[e * 8 + (jj)];    \
      }                                                                   \
    }
    XROW(1, M1, od0v, ot0v, 0)
    XROW(2, M2, od0v, ot0v, 1)
    XROW(3, M3, od0v, ot0v, 2)
    XROW(4, M4, od1v, ot1v, 3)
    XROW(5, M5, od1v, ot1v, 4)
    XROW(6, M6, od1v, ot1v, 5)
    XROW(7, M7, od1v, ot1v, 6)
    XROW(8, M8, od1v, ot1v, 7)
#undef XROW
#undef MBF
  }
  __syncthreads();

  {
    const int c = wv * 16 + e16;
    const int cksg = c >> 3, cj = c & 7;
#define WOUT(rr, MV)                                                       \
    {                                                                      \
      _Pragma("unroll")                                                    \
      for (int r = 0; r < 4; ++r) {                                        \
        int e = g * 4 + r;                                                 \
        mb[(((rr) * 8 + cksg) * 16 + e) * 8 + cj] = (__bf16)MV[r];         \
      }                                                                    \
    }
    WOUT(0, M0) WOUT(1, M1) WOUT(2, M2) WOUT(3, M3) WOUT(4, M4)
    WOUT(5, M5) WOUT(6, M6) WOUT(7, M7) WOUT(8, M8)
#undef WOUT
  }
  __syncthreads();

  // ---- conv2: rolled chains (single acc), wigner folded ----
  {
#define AF(row, ks) (*(const bf16x8*)(mb + (((row) * 8 + (ks)) * 16 + e16) * 8))
#define MF2(a, b, acc) acc = __builtin_amdgcn_mfma_f32_16x16x32_bf16(a, b, acc, 0, 0, 0)
#pragma unroll 1
    for (int gi = 0; gi < 2; ++gi) {
      const int c = (wv * 2 + gi) * 16 + e16;
      const int h = c >> 4;
      const float av0 = alp[(g * 4 + 0) * 8 + h];
      const float av1 = alp[(g * 4 + 1) * 8 + h];
      const float av2 = alp[(g * 4 + 2) * 8 + h];
      const float av3 = alp[(g * 4 + 3) * 8 + h];
      const float* wp0 = wib + (g * 4 + 0) * 81;
      const float* wp1 = wib + (g * 4 + 1) * 81;
      const float* wp2 = wib + (g * 4 + 2) * 81;
      const float* wp3 = wib + (g * 4 + 3) * 81;
      f32x4 oa[9];
#pragma unroll
      for (int i = 0; i < 9; ++i) oa[i] = (f32x4){0.f, 0.f, 0.f, 0.f};

      {
        bf16x8 a0 = AF(0, g), a1 = AF(0, 4 + g);
        bf16x8 a2 = AF(2, g), a3 = AF(2, 4 + g);
        bf16x8 a4 = AF(6, g), a5 = AF(6, 4 + g);
#pragma unroll 1
        for (int o = 0; o < 3; ++o) {
          const __bf16* wp = w0b + ((size_t)(g * 384) + o * 128 + c) * 8;
          f32x4 acc = {0.f, 0.f, 0.f, 0.f};
          MF2(a0, *(const bf16x8*)(wp + (size_t)0 * 4 * 384 * 8), acc);
          MF2(a1, *(const bf16x8*)(wp + (size_t)1 * 4 * 384 * 8), acc);
          MF2(a2, *(const bf16x8*)(wp + (size_t)2 * 4 * 384 * 8), acc);
          MF2(a3, *(const bf16x8*)(wp + (size_t)3 * 4 * 384 * 8), acc);
          MF2(a4, *(const bf16x8*)(wp + (size_t)4 * 4 * 384 * 8), acc);
          MF2(a5, *(const bf16x8*)(wp + (size_t)5 * 4 * 384 * 8), acc);
          const int j = (o == 0) ? 0 : (o == 1) ? 2 : 6;
          const float bb = b0[o * 128 + c];
          const float t0 = (acc[0] + bb) * av0;
          const float t1 = (acc[1] + bb) * av1;
          const float t2 = (acc[2] + bb) * av2;
          const float t3 = (acc[3] + bb) * av3;
#pragma unroll
          for (int i = 0; i < 9; ++i) {
            oa[i][0] += wp0[i * 9 + j] * t0;
            oa[i][1] += wp1[i * 9 + j] * t1;
            oa[i][2] += wp2[i * 9 + j] * t2;
            oa[i][3] += wp3[i * 9 + j] * t3;
          }
        }
      }
      {
        bf16x8 a0 = AF(3, g), a1 = AF(3, 4 + g);
        bf16x8 a2 = AF(7, g), a3 = AF(7, 4 + g);
        bf16x8 a4 = AF(1, g), a5 = AF(1, 4 + g);
        bf16x8 a6 = AF(5, g), a7 = AF(5, 4 + g);
#pragma unroll 1
        for (int o = 0; o < 4; ++o) {
          const __bf16* wp = w1n + ((size_t)(g * 512) + o * 128 + c) * 8;
          f32x4 acc = {0.f, 0.f, 0.f, 0.f};
          MF2(a0, *(const bf16x8*)(wp + (size_t)0 * 4 * 512 * 8), acc);
          MF2(a1, *(const bf16x8*)(wp + (size_t)1 * 4 * 512 * 8), acc);
          MF2(a2, *(const bf16x8*)(wp + (size_t)2 * 4 * 512 * 8), acc);
          MF2(a3, *(const bf16x8*)(wp + (size_t)3 * 4 * 512 * 8), acc);
          MF2(a4, *(const bf16x8*)(wp + (size_t)4 * 4 * 512 * 8), acc);
          MF2(a5, *(const bf16x8*)(wp + (size_t)5 * 4 * 512 * 8), acc);
          MF2(a6, *(const bf16x8*)(wp + (size_t)6 * 4 * 512 * 8), acc);
          MF2(a7, *(const bf16x8*)(wp + (size_t)7 * 4 * 512 * 8), acc);
          const int j = (o == 0) ? 3 : (o == 1) ? 7 : (o == 2) ? 1 : 5;
          const float t0 = acc[0] * av0;
          const float t1 = acc[1] * av1;
          const float t2 = acc[2] * av2;
          const float t3 = acc[3] * av3;
#pragma unroll
          for (int i = 0; i < 9; ++i) {
            oa[i][0] += wp0[i * 9 + j] * t0;
            oa[i][1] += wp1[i * 9 + j] * t1;
            oa[i][2] += wp2[i * 9 + j] * t2;
            oa[i][3] += wp3[i * 9 + j] * t3;
          }
        }
      }
      {
        bf16x8 a0 = AF(8, g), a1 = AF(8, 4 + g);
        bf16x8 a2 = AF(4, g), a3 = AF(4, 4 + g);
#pragma unroll 1
        for (int o = 0; o < 2; ++o) {
          const __bf16* wp = w2n + ((size_t)(g * 256) + o * 128 + c) * 8;
          f32x4 acc = {0.f, 0.f, 0.f, 0.f};
          MF2(a0, *(const bf16x8*)(wp + (size_t)0 * 4 * 256 * 8), acc);
          MF2(a1, *(const bf16x8*)(wp + (size_t)1 * 4 * 256 * 8), acc);
          MF2(a2, *(const bf16x8*)(wp + (size_t)2 * 4 * 256 * 8), acc);
          MF2(a3, *(const bf16x8*)(wp + (size_t)3 * 4 * 256 * 8), acc);
          const int j = (o == 0) ? 8 : 4;
          const float t0 = acc[0] * av0;
          const float t1 = acc[1] * av1;
          const float t2 = acc[2] * av2;
          const float t3 = acc[3] * av3;
#pragma unroll
          for (int i = 0; i < 9; ++i) {
            oa[i][0] += wp0[i * 9 + j] * t0;
            oa[i][1] += wp1[i * 9 + j] * t1;
            oa[i][2] += wp2[i * 9 + j] * t2;
            oa[i][3] += wp3[i * 9 + j] * t3;
          }
        }
      }
#pragma unroll
      for (int r = 0; r < 4; ++r) {
        float* np = node + (size_t)tnode[g * 4 + r] * 1152 + c;
#pragma unroll
        for (int i = 0; i < 9; ++i) atomicAdd(np + i * 128, oa[i][r]);
      }
    }
#undef MF2
#undef AF
#undef MF
  }
}

// ---------------------------------------------------------------------------
// per-node projection
// ---------------------------------------------------------------------------
__global__ __launch_bounds__(256) void k_proj(const float* __restrict__ node,
                                              const float* __restrict__ wT,
                                              const float* __restrict__ pb,
                                              float* __restrict__ out) {
  __shared__ __align__(16) float A[32 * 132];
  int k = blockIdx.y;
  int n0 = blockIdx.x * 32;
  const int lidx = (k == 0) ? 0 : (k <= 3 ? 1 : 2);
  int tid = threadIdx.x;
  for (int i = tid; i < 32 * 128; i += 256) {
    int nn = i >> 7, ii = i & 127;
    int n = n0 + nn;
    A[nn * 132 + ii] = (n < N_NODES) ? node[((size_t)n * 9 + k) * 128 + ii] : 0.f;
  }
  __syncthreads();
  int o = tid & 63, wid = tid >> 6;
  float acc[8] = {0.f, 0.f, 0.f, 0.f, 0.f, 0.f, 0.f, 0.f};
#pragma unroll 4
  for (int i = 0; i < 128; ++i) {
    float w = wT[lidx * 8192 + i * 64 + o];
#pragma unroll
    for (int r = 0; r < 8; ++r) acc[r] += A[(wid * 8 + r) * 132 + i] * w;
  }
  float bias = (k == 0) ? pb[o] : 0.f;
#pragma unroll
  for (int r = 0; r < 8; ++r) {
    int n = n0 + wid * 8 + r;
    if (n < N_NODES) out[((size_t)n * 9 + k) * 64 + o] = acc[r] + bias;
  }
}

// ---------------------------------------------------------------------------
extern "C" void kernel_launch(void* const* d_in, const int* in_sizes, int n_in,
                              void* d_out, int out_size, void* d_ws, size_t ws_size,
                              hipStream_t stream) {
  const float* x      = (const float*)d_in[0];
  const int*   an     = (const int*)d_in[1];
  const float* edist  = (const float*)d_in[2];
  const int*   eidx   = (const int*)d_in[3];
  const float* t_ij   = (const float*)d_in[4];
  const float* rl_ij  = (const float*)d_in[5];
  const float* wig    = (const float*)d_in[6];
  const float* winv   = (const float*)d_in[7];
  const float* semb   = (const float*)d_in[8];
  const float* temb   = (const float*)d_in[9];
  const float* rw1    = (const float*)d_in[10];
  const float* rb1    = (const float*)d_in[11];
  const float* rlnw   = (const float*)d_in[12];
  const float* rlnb   = (const float*)d_in[13];
  const float* rw2    = (const float*)d_in[14];
  const float* rb2    = (const float*)d_in[15];
  const float* c1w0   = (const float*)d_in[16];
  const float* c1b0   = (const float*)d_in[17];
  // d_in[18], d_in[19]: c1_wm1 / c1_wm2 — dead code in the reference
  const float* lnaw   = (const float*)d_in[20];
  const float* lnab   = (const float*)d_in[21];
  const float* adot   = (const float*)d_in[22];
  const float* gwh    = (const float*)d_in[23];
  const float* gwx    = (const float*)d_in[24];
  const float* gwt    = (const float*)d_in[25];
  const float* c2w0   = (const float*)d_in[26];
  const float* c2b0   = (const float*)d_in[27];
  const float* c2w1   = (const float*)d_in[28];
  const float* c2w2   = (const float*)d_in[29];
  const float* pw     = (const float*)d_in[30];
  const float* pb     = (const float*)d_in[31];
  float* out = (float*)d_out;

  char* p = (char*)d_ws;
  float* ws_attn  = (float*)p; p += (size_t)E_CNT * 320 * 4;
  float* ws_apre  = (float*)p; p += (size_t)E_CNT * 8 * 4;
  float* ws_ex    = (float*)p; p += (size_t)E_CNT * 8 * 4;
  unsigned* segk  = (unsigned*)p; p += (size_t)N_NODES * 8 * 4;
  float* denom    = (float*)p; p += (size_t)N_NODES * 8 * 4;
  float* node     = (float*)p; p += (size_t)N_NODES * 1152 * 4;
  float* wT       = (float*)p; p += (size_t)3 * 128 * 64 * 4;
  __bf16* w0r     = (__bf16*)p; p += (size_t)48 * 576 * 8 * 2;
  __bf16* w0b     = (__bf16*)p; p += (size_t)24 * 384 * 8 * 2;
  __bf16* w1n     = (__bf16*)p; p += (size_t)32 * 512 * 8 * 2;
  __bf16* w2n     = (__bf16*)p; p += (size_t)16 * 256 * 8 * 2;
  __bf16* rw1f    = (__bf16*)p; p += (size_t)40 * 128 * 8 * 2;
  __bf16* rw2f    = (__bf16*)p; p += (size_t)16 * 384 * 8 * 2;
  __bf16* gwhf    = (__bf16*)p; p += (size_t)8 * 64 * 8 * 2;
  __bf16* gwxf    = (__bf16*)p; p += (size_t)8 * 64 * 8 * 2;
  __bf16* gwtf    = (__bf16*)p; p += (size_t)16 * 64 * 8 * 2;

  hipMemsetAsync(segk, 0, N_NODES * 8 * 4, stream);
  hipMemsetAsync(denom, 0, N_NODES * 8 * 4, stream);
  hipMemsetAsync(node, 0, (size_t)N_NODES * 1152 * 4, stream);

  k_prep<<<372, 256, 0, stream>>>(c1w0, c2w0, c2w1, c2w2, rw1, rw2, gwh, gwx, gwt, pw,
                                  w0r, w0b, w1n, w2n, rw1f, rw2f, gwhf, gwxf, gwtf, wT);
  k_phase1<<<E_CNT / 16, 256, 0, stream>>>(x, an, edist, eidx, wig, semb, temb,
                                           rw1f, rb1, rlnw, rlnb, rw2f, rb2,
                                           w0r, c1b0, lnaw, lnab, adot,
                                           ws_attn, ws_apre, segk);
  k_expsum<<<(E_CNT * 8) / 256, 256, 0, stream>>>(ws_apre, eidx, segk, ws_ex, denom);
  k_phase2<<<E_CNT / 16, 256, 0, stream>>>(x, eidx, t_ij, rl_ij, winv,
                                           gwhf, gwxf, gwtf, w0b, c2b0, w1n, w2n,
                                           ws_attn, ws_ex, denom, node);
  k_proj<<<dim3((N_NODES + 31) / 32, 9), 256, 0, stream>>>(node, wT, pb, out);
}

// Round 16
// 765.438 us; speedup vs baseline: 1.2859x; 1.2859x over previous
//
#include <hip/hip_runtime.h>

#define E_CNT 80000
#define N_NODES 10000

typedef __attribute__((ext_vector_type(8))) __bf16 bf16x8;
typedef __attribute__((ext_vector_type(4))) float f32x4;

__device__ __forceinline__ float sigmoidf_(float x) { return 1.f / (1.f + __expf(-x)); }

__device__ __forceinline__ unsigned fkey(float f) {
  unsigned u = __float_as_uint(f);
  return (u & 0x80000000u) ? ~u : (u | 0x80000000u);
}
__device__ __forceinline__ float unfkey(unsigned k) {
  unsigned u = (k & 0x80000000u) ? (k & 0x7FFFFFFFu) : ~k;
  return __uint_as_float(u);
}

// ---------------------------------------------------------------------------
// Consolidated weight prep (R14).
// ---------------------------------------------------------------------------
__global__ __launch_bounds__(256) void k_prep(
    const float* __restrict__ c1w0, const float* __restrict__ c2w0,
    const float* __restrict__ c2w1, const float* __restrict__ c2w2,
    const float* __restrict__ rw1, const float* __restrict__ rw2,
    const float* __restrict__ gwh, const float* __restrict__ gwx,
    const float* __restrict__ gwt, const float* __restrict__ pw,
    __bf16* __restrict__ w0r, __bf16* __restrict__ w0b,
    __bf16* __restrict__ w1n, __bf16* __restrict__ w2n,
    __bf16* __restrict__ rw1f, __bf16* __restrict__ rw2f,
    __bf16* __restrict__ gwhf, __bf16* __restrict__ gwxf,
    __bf16* __restrict__ gwtf, float* __restrict__ wT) {
  int i = blockIdx.x * 256 + threadIdx.x;
  if (i < 27648) {
    int ksg = i / 576, col = i % 576;
#pragma unroll
    for (int j = 0; j < 8; ++j)
      w0r[(size_t)i * 8 + j] = (__bf16)c1w0[(size_t)(ksg * 8 + j) * 768 + col];
  } else if (i < 36864) {
    int ii = i - 27648;
    int ksg = ii / 384, col = ii % 384;
#pragma unroll
    for (int j = 0; j < 8; ++j)
      w0b[(size_t)ii * 8 + j] = (__bf16)c2w0[(size_t)(ksg * 8 + j) * 384 + col];
  } else if (i < 53248) {
    int ii = i - 36864;
    int ksg = ii >> 9, col = ii & 511;
    int o = col >> 7, c = col & 127;
    const int tc[4] = {0, 128, 256, 384};
    const int bc[4] = {256, 384, 0, 128};
    const float sg[4] = {-1.f, -1.f, 1.f, 1.f};
#pragma unroll
    for (int j = 0; j < 8; ++j) {
      int kk = ksg * 8 + j;
      float v = (kk < 128) ? c2w1[(size_t)kk * 512 + tc[o] + c]
                           : sg[o] * c2w1[(size_t)(kk - 128) * 512 + bc[o] + c];
      w1n[(size_t)ii * 8 + j] = (__bf16)v;
    }
  } else if (i < 57344) {
    int ii = i - 53248;
    int ksg = ii >> 8, col = ii & 255;
    int o = col >> 7, c = col & 127;
#pragma unroll
    for (int j = 0; j < 8; ++j) {
      int kk = ksg * 8 + j;
      float v;
      if (kk < 64) v = c2w2[(size_t)kk * 256 + (o == 0 ? c : c + 128)];
      else         v = (o == 0) ? -c2w2[(size_t)(kk - 64) * 256 + c + 128]
                                :  c2w2[(size_t)(kk - 64) * 256 + c];
      w2n[(size_t)ii * 8 + j] = (__bf16)v;
    }
  } else if (i < 62464) {
    int ii = i - 57344;
    int ksg = ii / 128, col = ii % 128;
#pragma unroll
    for (int j = 0; j < 8; ++j)
      rw1f[(size_t)ii * 8 + j] = (__bf16)rw1[(size_t)(ksg * 8 + j) * 128 + col];
  } else if (i < 68608) {
    int ii = i - 62464;
    int ksg = ii / 384, col = ii % 384;
#pragma unroll
    for (int j = 0; j < 8; ++j)
      rw2f[(size_t)ii * 8 + j] = (__bf16)rw2[(size_t)(ksg * 8 + j) * 768 + col];
  } else if (i < 69120) {
    int ii = i - 68608;
    int ksg = ii / 64, col = ii % 64;
#pragma unroll
    for (int j = 0; j < 8; ++j)
      gwhf[(size_t)ii * 8 + j] = (__bf16)gwh[(size_t)(ksg * 8 + j) * 64 + col];
  } else if (i < 69632) {
    int ii = i - 69120;
    int ksg = ii / 64, col = ii % 64;
#pragma unroll
    for (int j = 0; j < 8; ++j)
      gwxf[(size_t)ii * 8 + j] = (__bf16)gwx[(size_t)(ksg * 8 + j) * 64 + col];
  } else if (i < 70656) {
    int ii = i - 69632;
    int ksg = ii / 64, col = ii % 64;
#pragma unroll
    for (int j = 0; j < 8; ++j)
      gwtf[(size_t)ii * 8 + j] = (__bf16)gwt[(size_t)(ksg * 8 + j) * 64 + col];
  } else if (i < 95232) {
    int ii = i - 70656;
    int l = ii / 8192, r = ii % 8192, ir = r / 64, o = r % 64;
    wT[ii] = pw[(size_t)(l * 64 + o) * 128 + ir];
  }
}

// ---------------------------------------------------------------------------
// Phase 1 (R14 verbatim: R10 structure + fused segmax). 4 blocks/CU.
// ---------------------------------------------------------------------------
__global__ __launch_bounds__(256, 4) void k_phase1(
    const float* __restrict__ x, const int* __restrict__ an,
    const float* __restrict__ edist, const int* __restrict__ eidx,
    const float* __restrict__ wigner,
    const float* __restrict__ semb, const float* __restrict__ temb,
    const __bf16* __restrict__ rw1f, const float* __restrict__ rb1,
    const float* __restrict__ rlnw, const float* __restrict__ rlnb,
    const __bf16* __restrict__ rw2f, const float* __restrict__ rb2,
    const __bf16* __restrict__ w0r, const float* __restrict__ b0,
    const float* __restrict__ lnaw, const float* __restrict__ lnab,
    const float* __restrict__ adot,
    float* __restrict__ ws_attn, float* __restrict__ ws_apre,
    unsigned* __restrict__ segk)
{
  __shared__ __align__(16) float pool[6160];
  __shared__ __align__(16) float bufB[3136];
  __shared__ float wgs[432];
  __shared__ int sidx[16], tidx[16], ansh[16], anth[16];

  const int tid = threadIdx.x;
  const int e0 = blockIdx.x * 16;
  const int lane = tid & 63, wv4 = tid >> 6;
  const int erow = lane & 15, g = lane >> 4;

  __bf16* xe_bf = (__bf16*)pool;
  float* sb = bufB;
  __bf16* sb_bf = (__bf16*)(bufB + 2112);
  __bf16* a_lds2 = (__bf16*)bufB;

  if (tid < 16) {
    int s = eidx[e0 + tid], t = eidx[E_CNT + e0 + tid];
    sidx[tid] = s; tidx[tid] = t; ansh[tid] = an[s]; anth[tid] = an[t];
  }
  for (int i = tid; i < 432; i += 256) {
    int e = i / 27, r = i % 27, kk = r / 9, j = r % 9;
    int row = (kk == 0) ? 0 : (kk == 1 ? 2 : 6);
    wgs[i] = wigner[(size_t)(e0 + e) * 81 + row * 9 + j];
  }
  __syncthreads();

  for (int i = tid; i < 16 * 320; i += 256) {
    int e = i / 320, c = i % 320;
    float v;
    if (c < 64)       v = edist[(size_t)(e0 + e) * 64 + c];
    else if (c < 192) v = semb[ansh[e] * 128 + (c - 64)];
    else              v = temb[anth[e] * 128 + (c - 192)];
    xe_bf[(((c >> 3) * 16 + e) << 3) + (c & 7)] = (__bf16)v;
  }
  __syncthreads();

  {
    bf16x8 af2[10];
#pragma unroll
    for (int ks = 0; ks < 10; ++ks)
      af2[ks] = *(const bf16x8*)(xe_bf + ((ks * 4 + g) * 16 + erow) * 8);
#pragma unroll 1
    for (int tt = 0; tt < 2; ++tt) {
      int col = (wv4 * 2 + tt) * 16 + erow;
      f32x4 acc = {0.f, 0.f, 0.f, 0.f};
#pragma unroll
      for (int ks = 0; ks < 10; ++ks)
        acc = __builtin_amdgcn_mfma_f32_16x16x32_bf16(
            af2[ks], *(const bf16x8*)(rw1f + ((size_t)((ks * 4 + g) * 128) + col) * 8), acc, 0, 0, 0);
      float bb = rb1[col];
#pragma unroll
      for (int r = 0; r < 4; ++r) sb[(g * 4 + r) * 132 + col] = acc[r] + bb;
    }
  }
  __syncthreads();

  {
    int wid = tid >> 6, ln = tid & 63;
    for (int e = wid; e < 16; e += 4) {
      float v0 = sb[e * 132 + ln], v1 = sb[e * 132 + ln + 64];
      float s1 = v0 + v1, s2 = v0 * v0 + v1 * v1;
#pragma unroll
      for (int m = 32; m >= 1; m >>= 1) {
        s1 += __shfl_xor(s1, m);
        s2 += __shfl_xor(s2, m);
      }
      float mu = s1 * (1.f / 128.f);
      float var = s2 * (1.f / 128.f) - mu * mu;
      float rstd = rsqrtf(var + 1e-5f);
      float y0 = (v0 - mu) * rstd * rlnw[ln] + rlnb[ln];
      float y1 = (v1 - mu) * rstd * rlnw[ln + 64] + rlnb[ln + 64];
      sb[e * 132 + ln]      = y0 * sigmoidf_(y0) * (1.f / 0.6f);
      sb[e * 132 + ln + 64] = y1 * sigmoidf_(y1) * (1.f / 0.6f);
    }
  }
  __syncthreads();

  {
    int ksg = tid >> 4, e = tid & 15;
    const float* sp = sb + e * 132 + ksg * 8;
    float4 u0 = *(const float4*)sp;
    float4 u1 = *(const float4*)(sp + 4);
    bf16x8 v;
    v[0] = (__bf16)u0.x; v[1] = (__bf16)u0.y; v[2] = (__bf16)u0.z; v[3] = (__bf16)u0.w;
    v[4] = (__bf16)u1.x; v[5] = (__bf16)u1.y; v[6] = (__bf16)u1.z; v[7] = (__bf16)u1.w;
    *(bf16x8*)(sb_bf + (ksg * 16 + e) * 8) = v;
  }
  __syncthreads();

  float* rbuf = pool;
  {
    bf16x8 af3[4];
#pragma unroll
    for (int ks = 0; ks < 4; ++ks)
      af3[ks] = *(const bf16x8*)(sb_bf + ((ks * 4 + g) * 16 + erow) * 8);
#pragma unroll 1
    for (int tt = 0; tt < 6; ++tt) {
      int col = (wv4 * 6 + tt) * 16 + erow;
      f32x4 acc = {0.f, 0.f, 0.f, 0.f};
#pragma unroll
      for (int ks = 0; ks < 4; ++ks)
        acc = __builtin_amdgcn_mfma_f32_16x16x32_bf16(
            af3[ks], *(const bf16x8*)(rw2f + ((size_t)((ks * 4 + g) * 384) + col) * 8), acc, 0, 0, 0);
      float bb = rb2[col];
#pragma unroll
      for (int r = 0; r < 4; ++r) rbuf[(g * 4 + r) * 385 + col] = acc[r] + bb;
    }
  }
  __syncthreads();

  {
    int e = tid & 15, cg = tid >> 4;
    int c0 = cg * 8;
    const float* xb = (c0 < 64) ? (x + (size_t)sidx[e] * 576 + c0)
                                : (x + (size_t)tidx[e] * 576 + (c0 - 64));
    float xc[9][8];
#pragma unroll
    for (int j = 0; j < 9; ++j) {
      float4 u0 = *(const float4*)(xb + j * 64);
      float4 u1 = *(const float4*)(xb + j * 64 + 4);
      xc[j][0] = u0.x; xc[j][1] = u0.y; xc[j][2] = u0.z; xc[j][3] = u0.w;
      xc[j][4] = u1.x; xc[j][5] = u1.y; xc[j][6] = u1.z; xc[j][7] = u1.w;
    }
#pragma unroll
    for (int kk = 0; kk < 3; ++kk) {
      float wv[9];
#pragma unroll
      for (int j = 0; j < 9; ++j) wv[j] = wgs[e * 27 + kk * 9 + j];
      __bf16* ap = a_lds2 + ((kk * 16 + cg) * 16 + e) * 8;
#pragma unroll
      for (int cu = 0; cu < 8; ++cu) {
        float m = 0.f;
#pragma unroll
        for (int j = 0; j < 9; ++j) m += wv[j] * xc[j][cu];
        int colc = kk * 128 + c0 + cu;
        ap[cu] = (__bf16)(m * rbuf[e * 385 + colc]);
      }
    }
  }
  __syncthreads();

  float* sb5 = pool;
  {
    bf16x8 af[12];
#pragma unroll
    for (int ks = 0; ks < 12; ++ks)
      af[ks] = *(const bf16x8*)(a_lds2 + ((ks * 4 + g) * 16 + erow) * 8);
#pragma unroll 1
    for (int tt = 0; tt < 9; ++tt) {
      int tile = wv4 * 9 + tt;
      int col = tile * 16 + erow;
      f32x4 acc = {0.f, 0.f, 0.f, 0.f};
#pragma unroll
      for (int ks = 0; ks < 12; ++ks) {
        bf16x8 bf = *(const bf16x8*)(w0r + ((size_t)((ks * 4 + g) * 576) + col) * 8);
        acc = __builtin_amdgcn_mfma_f32_16x16x32_bf16(af[ks], bf, acc, 0, 0, 0);
      }
      if (tile < 16) {
#pragma unroll
        for (int r = 0; r < 4; ++r) sb5[(g * 4 + r) * 260 + col] = acc[r];
      } else {
        float bb = b0[col];
#pragma unroll
        for (int r = 0; r < 4; ++r)
          ws_attn[(size_t)(e0 + g * 4 + r) * 320 + (col - 256)] = acc[r] + bb;
      }
    }
  }
  __syncthreads();

  {
    float bb = b0[tid];
    int h = tid >> 5, kk = tid & 31;
    float lw = lnaw[kk], lb = lnab[kk], ad = adot[h * 32 + kk];
#pragma unroll
    for (int e = 0; e < 16; ++e) {
      float v = sb5[e * 260 + tid] + bb;
      float s1 = v, s2 = v * v;
#pragma unroll
      for (int m = 16; m >= 1; m >>= 1) {
        s1 += __shfl_xor(s1, m);
        s2 += __shfl_xor(s2, m);
      }
      float mu = s1 * (1.f / 32.f);
      float var = s2 * (1.f / 32.f) - mu * mu;
      float rstd = rsqrtf(var + 1e-5f);
      float xn = (v - mu) * rstd * lw + lb;
      float sl = 0.6f * xn + 0.4f * xn * (2.f * sigmoidf_(xn) - 1.f);
      float p = sl * ad;
#pragma unroll
      for (int m = 16; m >= 1; m >>= 1) p += __shfl_xor(p, m);
      if (kk == 0) {
        ws_apre[(size_t)(e0 + e) * 8 + h] = p;
        atomicMax(&segk[tidx[e] * 8 + h], fkey(p));
      }
    }
  }
}

// ---------------------------------------------------------------------------
// exp-sum (segmax fused into phase1)
// ---------------------------------------------------------------------------
__global__ __launch_bounds__(256) void k_expsum(const float* __restrict__ apre,
                                                const int* __restrict__ eidx,
                                                const unsigned* __restrict__ segk,
                                                float* __restrict__ ex_out,
                                                float* __restrict__ denom) {
  int idx = blockIdx.x * 256 + threadIdx.x;
  if (idx >= E_CNT * 8) return;
  int e = idx >> 3, h = idx & 7;
  int t = eidx[E_CNT + e];
  float m = unfkey(segk[t * 8 + h]);
  float ex = __expf(apre[idx] - m);
  ex_out[idx] = ex;
  atomicAdd(&denom[t * 8 + h], ex);
}

// ---------------------------------------------------------------------------
// Phase 2: R13 structure, launch bound (256,3) — the only non-spilling
// setting (hipcc budgets ~256/N VGPRs: N=3 -> 84, N>=4 spills this kernel).
// ---------------------------------------------------------------------------
__global__ __launch_bounds__(256, 3) void k_phase2(
    const float* __restrict__ x, const int* __restrict__ eidx,
    const float* __restrict__ t_ij, const float* __restrict__ rl_ij,
    const float* __restrict__ winv,
    const __bf16* __restrict__ gwhf, const __bf16* __restrict__ gwxf, const __bf16* __restrict__ gwtf,
    const __bf16* __restrict__ w0b, const float* __restrict__ b0,
    const __bf16* __restrict__ w1n, const __bf16* __restrict__ w2n,
    const float* __restrict__ ws_attn, const float* __restrict__ ws_ex,
    const float* __restrict__ denom,
    float* __restrict__ node)
{
  __shared__ __align__(16) __bf16 mb[9 * 8 * 16 * 8];
  __shared__ __align__(16) __bf16 tbf[16 * 16 * 8];
  __shared__ float wib[16 * 81];
  __shared__ float alp[128];
  __shared__ float rlb[128];
  __shared__ float malp[16];
  __shared__ int tnode[16];

  const int tid = threadIdx.x;
  const int e0 = blockIdx.x * 16;
  const int lane = tid & 63, wv = tid >> 6;
  const int e16 = lane & 15, g = lane >> 4;

  if (tid < 16) tnode[tid] = eidx[E_CNT + e0 + tid];
  __syncthreads();

  if (tid < 128) {
    int e = tid >> 3, h = tid & 7;
    float ex = ws_ex[(size_t)(e0 + e) * 8 + h];
    alp[tid] = ex / (denom[tnode[e] * 8 + h] + 1e-16f);
  } else {
    int i = tid - 128;
    rlb[i] = rl_ij[(size_t)(e0 + (i >> 3)) * 8 + (i & 7)];
  }
  for (int i = tid; i < 16 * 81; i += 256)
    wib[i] = winv[(size_t)(e0 + i / 81) * 81 + i % 81];

  for (int i = tid; i < 1152; i += 256) {
    int e = i / 72, rk = i % 72;
    const float* sp = x + (size_t)tnode[e] * 576 + rk * 8;
    float4 u0 = *(const float4*)sp;
    float4 u1 = *(const float4*)(sp + 4);
    bf16x8 v;
    v[0] = (__bf16)u0.x; v[1] = (__bf16)u0.y; v[2] = (__bf16)u0.z; v[3] = (__bf16)u0.w;
    v[4] = (__bf16)u1.x; v[5] = (__bf16)u1.y; v[6] = (__bf16)u1.z; v[7] = (__bf16)u1.w;
    *(bf16x8*)(mb + ((size_t)rk * 16 + e) * 8) = v;
  }
  {
    int e = tid >> 4, ksg = tid & 15;
    const float* sp = t_ij + (size_t)(e0 + e) * 128 + ksg * 8;
    float4 u0 = *(const float4*)sp;
    float4 u1 = *(const float4*)(sp + 4);
    bf16x8 v;
    v[0] = (__bf16)u0.x; v[1] = (__bf16)u0.y; v[2] = (__bf16)u0.z; v[3] = (__bf16)u0.w;
    v[4] = (__bf16)u1.x; v[5] = (__bf16)u1.y; v[6] = (__bf16)u1.z; v[7] = (__bf16)u1.w;
    *(bf16x8*)(tbf + ((size_t)ksg * 16 + e) * 8) = v;
  }
  __syncthreads();
  if (tid < 16) {
    float s = 0.f;
#pragma unroll
    for (int h = 0; h < 8; ++h) s += alp[tid * 8 + h];
    malp[tid] = s * 0.125f;
  }
  __syncthreads();

  // ---- gates (per-wave o-tile) + fused combine -> M0..M8 in registers ----
  f32x4 M0, M1, M2, M3, M4, M5, M6, M7, M8;
  {
    const int c = wv * 16 + e16;
#define MF(a, b, acc) acc = __builtin_amdgcn_mfma_f32_16x16x32_bf16(a, b, acc, 0, 0, 0)
#define MBF(row, ksg) (*(const bf16x8*)(mb + (((row) * 8 + (ksg)) * 16 + e16) * 8))
    f32x4 tv4;
    {
      f32x4 acc = {0.f, 0.f, 0.f, 0.f};
#pragma unroll
      for (int ks = 0; ks < 4; ++ks)
        MF(*(const bf16x8*)(tbf + ((ks * 4 + g) * 16 + e16) * 8),
           *(const bf16x8*)(gwtf + ((size_t)((ks * 4 + g) * 64) + c) * 8), acc);
#pragma unroll
      for (int r = 0; r < 4; ++r) { float v = acc[r]; tv4[r] = v * sigmoidf_(v); }
    }
    f32x4 hv4;
    {
      f32x4 acc = {0.f, 0.f, 0.f, 0.f};
      MF(MBF(0, g), *(const bf16x8*)(gwhf + ((size_t)(g * 64) + c) * 8), acc);
      MF(MBF(0, 4 + g), *(const bf16x8*)(gwhf + ((size_t)((4 + g) * 64) + c) * 8), acc);
#pragma unroll
      for (int r = 0; r < 4; ++r) { float v = acc[r]; hv4[r] = v * sigmoidf_(v); }
    }
    f32x4 osv, od0v, od1v, ot0v, ot1v;
#pragma unroll
    for (int r = 0; r < 4; ++r) {
      int e = g * 4 + r;
      float ml = malp[e];
      const float* wsb = ws_attn + (size_t)(e0 + e) * 320;
      osv[r]  = wsb[c] * ml;
      od0v[r] = wsb[64 + c] * ml;
      od1v[r] = wsb[128 + c] * ml;
      ot0v[r] = wsb[192 + c] * ml;
      ot1v[r] = wsb[256 + c] * ml;
    }
#pragma unroll
    for (int r = 0; r < 4; ++r) M0[r] = osv[r] * hv4[r];
    bf16x8 bx0 = *(const bf16x8*)(gwxf + ((size_t)(g * 64) + c) * 8);
    bf16x8 bx1 = *(const bf16x8*)(gwxf + ((size_t)((4 + g) * 64) + c) * 8);
#define XROW(rr, MV, odv, otv, jj)                                        \
    {                                                                     \
      f32x4 acc = {0.f, 0.f, 0.f, 0.f};                                   \
      MF(MBF(rr, g), bx0, acc);                                           \
      MF(MBF(rr, 4 + g), bx1, acc);                                       \
      _Pragma("unroll")                                                   \
      for (int r = 0; r < 4; ++r) {                                       \
        int e = g * 4 + r;                                                \
        MV[r] = odv[r] * acc[r] + otv[r] * tv4[r] * rlb[e * 8 + (jj)];    \
      }                                                                   \
    }
    XROW(1, M1, od0v, ot0v, 0)
    XROW(2, M2, od0v, ot0v, 1)
    XROW(3, M3, od0v, ot0v, 2)
    XROW(4, M4, od1v, ot1v, 3)
    XROW(5, M5, od1v, ot1v, 4)
    XROW(6, M6, od1v, ot1v, 5)
    XROW(7, M7, od1v, ot1v, 6)
    XROW(8, M8, od1v, ot1v, 7)
#undef XROW
#undef MBF
  }
  __syncthreads();

  {
    const int c = wv * 16 + e16;
    const int cksg = c >> 3, cj = c & 7;
#define WOUT(rr, MV)                                                       \
    {                                                                      \
      _Pragma("unroll")                                                    \
      for (int r = 0; r < 4; ++r) {                                        \
        int e = g * 4 + r;                                                 \
        mb[(((rr) * 8 + cksg) * 16 + e) * 8 + cj] = (__bf16)MV[r];         \
      }                                                                    \
    }
    WOUT(0, M0) WOUT(1, M1) WOUT(2, M2) WOUT(3, M3) WOUT(4, M4)
    WOUT(5, M5) WOUT(6, M6) WOUT(7, M7) WOUT(8, M8)
#undef WOUT
  }
  __syncthreads();

  // ---- conv2: rolled chains (single acc), wigner folded ----
  {
#define AF(row, ks) (*(const bf16x8*)(mb + (((row) * 8 + (ks)) * 16 + e16) * 8))
#define MF2(a, b, acc) acc = __builtin_amdgcn_mfma_f32_16x16x32_bf16(a, b, acc, 0, 0, 0)
#pragma unroll 1
    for (int gi = 0; gi < 2; ++gi) {
      const int c = (wv * 2 + gi) * 16 + e16;
      const int h = c >> 4;
      const float av0 = alp[(g * 4 + 0) * 8 + h];
      const float av1 = alp[(g * 4 + 1) * 8 + h];
      const float av2 = alp[(g * 4 + 2) * 8 + h];
      const float av3 = alp[(g * 4 + 3) * 8 + h];
      const float* wp0 = wib + (g * 4 + 0) * 81;
      const float* wp1 = wib + (g * 4 + 1) * 81;
      const float* wp2 = wib + (g * 4 + 2) * 81;
      const float* wp3 = wib + (g * 4 + 3) * 81;
      f32x4 oa[9];
#pragma unroll
      for (int i = 0; i < 9; ++i) oa[i] = (f32x4){0.f, 0.f, 0.f, 0.f};

      {
        bf16x8 a0 = AF(0, g), a1 = AF(0, 4 + g);
        bf16x8 a2 = AF(2, g), a3 = AF(2, 4 + g);
        bf16x8 a4 = AF(6, g), a5 = AF(6, 4 + g);
#pragma unroll 1
        for (int o = 0; o < 3; ++o) {
          const __bf16* wp = w0b + ((size_t)(g * 384) + o * 128 + c) * 8;
          f32x4 acc = {0.f, 0.f, 0.f, 0.f};
          MF2(a0, *(const bf16x8*)(wp + (size_t)0 * 4 * 384 * 8), acc);
          MF2(a1, *(const bf16x8*)(wp + (size_t)1 * 4 * 384 * 8), acc);
          MF2(a2, *(const bf16x8*)(wp + (size_t)2 * 4 * 384 * 8), acc);
          MF2(a3, *(const bf16x8*)(wp + (size_t)3 * 4 * 384 * 8), acc);
          MF2(a4, *(const bf16x8*)(wp + (size_t)4 * 4 * 384 * 8), acc);
          MF2(a5, *(const bf16x8*)(wp + (size_t)5 * 4 * 384 * 8), acc);
          const int j = (o == 0) ? 0 : (o == 1) ? 2 : 6;
          const float bb = b0[o * 128 + c];
          const float t0 = (acc[0] + bb) * av0;
          const float t1 = (acc[1] + bb) * av1;
          const float t2 = (acc[2] + bb) * av2;
          const float t3 = (acc[3] + bb) * av3;
#pragma unroll
          for (int i = 0; i < 9; ++i) {
            oa[i][0] += wp0[i * 9 + j] * t0;
            oa[i][1] += wp1[i * 9 + j] * t1;
            oa[i][2] += wp2[i * 9 + j] * t2;
            oa[i][3] += wp3[i * 9 + j] * t3;
          }
        }
      }
      {
        bf16x8 a0 = AF(3, g), a1 = AF(3, 4 + g);
        bf16x8 a2 = AF(7, g), a3 = AF(7, 4 + g);
        bf16x8 a4 = AF(1, g), a5 = AF(1, 4 + g);
        bf16x8 a6 = AF(5, g), a7 = AF(5, 4 + g);
#pragma unroll 1
        for (int o = 0; o < 4; ++o) {
          const __bf16* wp = w1n + ((size_t)(g * 512) + o * 128 + c) * 8;
          f32x4 acc = {0.f, 0.f, 0.f, 0.f};
          MF2(a0, *(const bf16x8*)(wp + (size_t)0 * 4 * 512 * 8), acc);
          MF2(a1, *(const bf16x8*)(wp + (size_t)1 * 4 * 512 * 8), acc);
          MF2(a2, *(const bf16x8*)(wp + (size_t)2 * 4 * 512 * 8), acc);
          MF2(a3, *(const bf16x8*)(wp + (size_t)3 * 4 * 512 * 8), acc);
          MF2(a4, *(const bf16x8*)(wp + (size_t)4 * 4 * 512 * 8), acc);
          MF2(a5, *(const bf16x8*)(wp + (size_t)5 * 4 * 512 * 8), acc);
          MF2(a6, *(const bf16x8*)(wp + (size_t)6 * 4 * 512 * 8), acc);
          MF2(a7, *(const bf16x8*)(wp + (size_t)7 * 4 * 512 * 8), acc);
          const int j = (o == 0) ? 3 : (o == 1) ? 7 : (o == 2) ? 1 : 5;
          const float t0 = acc[0] * av0;
          const float t1 = acc[1] * av1;
          const float t2 = acc[2] * av2;
          const float t3 = acc[3] * av3;
#pragma unroll
          for (int i = 0; i < 9; ++i) {
            oa[i][0] += wp0[i * 9 + j] * t0;
            oa[i][1] += wp1[i * 9 + j] * t1;
            oa[i][2] += wp2[i * 9 + j] * t2;
            oa[i][3] += wp3[i * 9 + j] * t3;
          }
        }
      }
      {
        bf16x8 a0 = AF(8, g), a1 = AF(8, 4 + g);
        bf16x8 a2 = AF(4, g), a3 = AF(4, 4 + g);
#pragma unroll 1
        for (int o = 0; o < 2; ++o) {
          const __bf16* wp = w2n + ((size_t)(g * 256) + o * 128 + c) * 8;
          f32x4 acc = {0.f, 0.f, 0.f, 0.f};
          MF2(a0, *(const bf16x8*)(wp + (size_t)0 * 4 * 256 * 8), acc);
          MF2(a1, *(const bf16x8*)(wp + (size_t)1 * 4 * 256 * 8), acc);
          MF2(a2, *(const bf16x8*)(wp + (size_t)2 * 4 * 256 * 8), acc);
          MF2(a3, *(const bf16x8*)(wp + (size_t)3 * 4 * 256 * 8), acc);
          const int j = (o == 0) ? 8 : 4;
          const float t0 = acc[0] * av0;
          const float t1 = acc[1] * av1;
          const float t2 = acc[2] * av2;
          const float t3 = acc[3] * av3;
#pragma unroll
          for (int i = 0; i < 9; ++i) {
            oa[i][0] += wp0[i * 9 + j] * t0;
            oa[i][1] += wp1[i * 9 + j] * t1;
            oa[i][2] += wp2[i * 9 + j] * t2;
            oa[i][3] += wp3[i * 9 + j] * t3;
          }
        }
      }
#pragma unroll
      for (int r = 0; r < 4; ++r) {
        float* np = node + (size_t)tnode[g * 4 + r] * 1152 + c;
#pragma unroll
        for (int i = 0; i < 9; ++i) atomicAdd(np + i * 128, oa[i][r]);
      }
    }
#undef MF2
#undef AF
#undef MF
  }
}

// ---------------------------------------------------------------------------
// per-node projection
// ---------------------------------------------------------------------------
__global__ __launch_bounds__(256) void k_proj(const float* __restrict__ node,
                                              const float* __restrict__ wT,
                                              const float* __restrict__ pb,
                                              float* __restrict__ out) {
  __shared__ __align__(16) float A[32 * 132];
  int k = blockIdx.y;
  int n0 = blockIdx.x * 32;
  const int lidx = (k == 0) ? 0 : (k <= 3 ? 1 : 2);
  int tid = threadIdx.x;
  for (int i = tid; i < 32 * 128; i += 256) {
    int nn = i >> 7, ii = i & 127;
    int n = n0 + nn;
    A[nn * 132 + ii] = (n < N_NODES) ? node[((size_t)n * 9 + k) * 128 + ii] : 0.f;
  }
  __syncthreads();
  int o = tid & 63, wid = tid >> 6;
  float acc[8] = {0.f, 0.f, 0.f, 0.f, 0.f, 0.f, 0.f, 0.f};
#pragma unroll 4
  for (int i = 0; i < 128; ++i) {
    float w = wT[lidx * 8192 + i * 64 + o];
#pragma unroll
    for (int r = 0; r < 8; ++r) acc[r] += A[(wid * 8 + r) * 132 + i] * w;
  }
  float bias = (k == 0) ? pb[o] : 0.f;
#pragma unroll
  for (int r = 0; r < 8; ++r) {
    int n = n0 + wid * 8 + r;
    if (n < N_NODES) out[((size_t)n * 9 + k) * 64 + o] = acc[r] + bias;
  }
}

// ---------------------------------------------------------------------------
extern "C" void kernel_launch(void* const* d_in, const int* in_sizes, int n_in,
                              void* d_out, int out_size, void* d_ws, size_t ws_size,
                              hipStream_t stream) {
  const float* x      = (const float*)d_in[0];
  const int*   an     = (const int*)d_in[1];
  const float* edist  = (const float*)d_in[2];
  const int*   eidx   = (const int*)d_in[3];
  const float* t_ij   = (const float*)d_in[4];
  const float* rl_ij  = (const float*)d_in[5];
  const float* wig    = (const float*)d_in[6];
  const float* winv   = (const float*)d_in[7];
  const float* semb   = (const float*)d_in[8];
  const float* temb   = (const float*)d_in[9];
  const float* rw1    = (const float*)d_in[10];
  const float* rb1    = (const float*)d_in[11];
  const float* rlnw   = (const float*)d_in[12];
  const float* rlnb   = (const float*)d_in[13];
  const float* rw2    = (const float*)d_in[14];
  const float* rb2    = (const float*)d_in[15];
  const float* c1w0   = (const float*)d_in[16];
  const float* c1b0   = (const float*)d_in[17];
  // d_in[18], d_in[19]: c1_wm1 / c1_wm2 — dead code in the reference
  const float* lnaw   = (const float*)d_in[20];
  const float* lnab   = (const float*)d_in[21];
  const float* adot   = (const float*)d_in[22];
  const float* gwh    = (const float*)d_in[23];
  const float* gwx    = (const float*)d_in[24];
  const float* gwt    = (const float*)d_in[25];
  const float* c2w0   = (const float*)d_in[26];
  const float* c2b0   = (const float*)d_in[27];
  const float* c2w1   = (const float*)d_in[28];
  const float* c2w2   = (const float*)d_in[29];
  const float* pw     = (const float*)d_in[30];
  const float* pb     = (const float*)d_in[31];
  float* out = (float*)d_out;

  char* p = (char*)d_ws;
  float* ws_attn  = (float*)p; p += (size_t)E_CNT * 320 * 4;
  float* ws_apre  = (float*)p; p += (size_t)E_CNT * 8 * 4;
  float* ws_ex    = (float*)p; p += (size_t)E_CNT * 8 * 4;
  unsigned* segk  = (unsigned*)p; p += (size_t)N_NODES * 8 * 4;
  float* denom    = (float*)p; p += (size_t)N_NODES * 8 * 4;
  float* node     = (float*)p; p += (size_t)N_NODES * 1152 * 4;
  float* wT       = (float*)p; p += (size_t)3 * 128 * 64 * 4;
  __bf16* w0r     = (__bf16*)p; p += (size_t)48 * 576 * 8 * 2;
  __bf16* w0b     = (__bf16*)p; p += (size_t)24 * 384 * 8 * 2;
  __bf16* w1n     = (__bf16*)p; p += (size_t)32 * 512 * 8 * 2;
  __bf16* w2n     = (__bf16*)p; p += (size_t)16 * 256 * 8 * 2;
  __bf16* rw1f    = (__bf16*)p; p += (size_t)40 * 128 * 8 * 2;
  __bf16* rw2f    = (__bf16*)p; p += (size_t)16 * 384 * 8 * 2;
  __bf16* gwhf    = (__bf16*)p; p += (size_t)8 * 64 * 8 * 2;
  __bf16* gwxf    = (__bf16*)p; p += (size_t)8 * 64 * 8 * 2;
  __bf16* gwtf    = (__bf16*)p; p += (size_t)16 * 64 * 8 * 2;

  hipMemsetAsync(segk, 0, N_NODES * 8 * 4, stream);
  hipMemsetAsync(denom, 0, N_NODES * 8 * 4, stream);
  hipMemsetAsync(node, 0, (size_t)N_NODES * 1152 * 4, stream);

  k_prep<<<372, 256, 0, stream>>>(c1w0, c2w0, c2w1, c2w2, rw1, rw2, gwh, gwx, gwt, pw,
                                  w0r, w0b, w1n, w2n, rw1f, rw2f, gwhf, gwxf, gwtf, wT);
  k_phase1<<<E_CNT / 16, 256, 0, stream>>>(x, an, edist, eidx, wig, semb, temb,
                                           rw1f, rb1, rlnw, rlnb, rw2f, rb2,
                                           w0r, c1b0, lnaw, lnab, adot,
                                           ws_attn, ws_apre, segk);
  k_expsum<<<(E_CNT * 8) / 256, 256, 0, stream>>>(ws_apre, eidx, segk, ws_ex, denom);
  k_phase2<<<E_CNT / 16, 256, 0, stream>>>(x, eidx, t_ij, rl_ij, winv,
                                           gwhf, gwxf, gwtf, w0b, c2b0, w1n, w2n,
                                           ws_attn, ws_ex, denom, node);
  k_proj<<<dim3((N_NODES + 31) / 32, 9), 256, 0, stream>>>(node, wT, pb, out);
}